// Round 10
// baseline (315.715 us; speedup 1.0000x reference)
//
#include <hip/hip_runtime.h>
#include <hip/hip_bf16.h>

#define NNODE 1024
#define DIM 128
#define HEADS 8
#define DK 16
#define EDIM 16
#define BN 8               // target nodes per attn block
#define MSPLIT 8           // compacted-list splits per node group
#define LOG2E 1.44269504f

// ---------------- Kernel 1: LayerNorm + QKV projection ----------------
__global__ __launch_bounds__(384)
void ln_qkv_kernel(const float* __restrict__ x,
                   const float* __restrict__ Wq, const float* __restrict__ bq,
                   const float* __restrict__ Wk, const float* __restrict__ bk,
                   const float* __restrict__ Wv, const float* __restrict__ bv,
                   const float* __restrict__ gamma, const float* __restrict__ beta,
                   float* __restrict__ qg, float* __restrict__ kg, float* __restrict__ vg) {
    const int n = blockIdx.x;
    const int t = threadIdx.x;
    __shared__ float hrow[DIM];
    __shared__ float part[4];

    float xv = 0.f;
    if (t < 128) {
        xv = x[n * DIM + t];
        float v = xv;
        #pragma unroll
        for (int off = 32; off >= 1; off >>= 1) v += __shfl_xor(v, off);
        if ((t & 63) == 0) part[t >> 6] = v;
    }
    __syncthreads();
    const float mu = (part[0] + part[1]) * (1.0f / DIM);
    const float dx = xv - mu;
    if (t < 128) {
        float v = dx * dx;
        #pragma unroll
        for (int off = 32; off >= 1; off >>= 1) v += __shfl_xor(v, off);
        if ((t & 63) == 0) part[2 + (t >> 6)] = v;
    }
    __syncthreads();
    if (t < 128) {
        const float var = (part[2] + part[3]) * (1.0f / DIM);
        hrow[t] = dx * rsqrtf(var + 1e-5f) * gamma[t] + beta[t];
    }
    __syncthreads();

    const int which = t >> 7;          // 0,1,2 -> q,k,v (wave-uniform)
    const int col = t & 127;
    const float* W = (which == 0) ? Wq : (which == 1) ? Wk : Wv;
    const float* b = (which == 0) ? bq : (which == 1) ? bk : bv;
    float* o       = (which == 0) ? qg : (which == 1) ? kg : vg;
    float acc = b[col];
    #pragma unroll 16
    for (int i = 0; i < DIM; ++i) acc = fmaf(hrow[i], W[i * DIM + col], acc);
    o[n * DIM + col] = acc;
}

// ---------------- Kernel 1b: mask compaction ----------------
// One wave per target node: ascending list of valid source indices (u16) + count.
// ~50% of mask entries are 0 -> halves the attention work and the ef stream.
__global__ __launch_bounds__(64)
void mask_scan_kernel(const int* __restrict__ mask,
                      unsigned short* __restrict__ idx, int* __restrict__ cnt) {
    const int n = blockIdx.x;
    const int l = threadIdx.x;       // 0..63
    int base = 0;
    #pragma unroll 1
    for (int c = 0; c < NNODE / 64; ++c) {
        const int m = c * 64 + l;
        const bool v = mask[(size_t)n * NNODE + m] != 0;
        const unsigned long long b = __ballot(v);
        const int pre = __popcll(b & ((1ull << l) - 1ull));
        if (v) idx[(size_t)n * NNODE + base + pre] = (unsigned short)m;
        base += __popcll(b);
    }
    if (l == 0) cnt[n] = base;
}

// ---------------- Kernel 2: attention partials over compacted edges ----------------
// grid = (1024/BN)*MSPLIT = 1024 blocks; 256 threads = (nl: t>>5, mslot: (t>>3)&3, h: t&7)
// ZERO LDS, ZERO barriers. Each thread owns ONE (n,h) pair (live state ~65 f32 vs
// round-9's ~114 paired) and walks the compacted valid-m list with stride 32
// (4 mslots x 8 ms-blocks). The 8 h-lanes of an octet share the (n,m) row: ef/idx
// loads broadcast. Next-index prefetch keeps the idx load off the critical path.
// Masked terms are exact zeros in the reference (exp(-10000)=0) -> skipping them
// is bit-compatible modulo fp sum order (already reordered since round 1; passes).
// No LDS atomics (round 7), no VGPR clamp below live state (round 6).
__global__ __launch_bounds__(256, 2)
void attn_kernel(const float* __restrict__ qg, const float* __restrict__ kg,
                 const float* __restrict__ vg, const float* __restrict__ ef,
                 const unsigned short* __restrict__ idx, const int* __restrict__ cnt,
                 const float* __restrict__ Wae, const float* __restrict__ bae,
                 float* __restrict__ acc) {
    const int t = threadIdx.x;
    const int h = t & 7;
    const int mslot = (t >> 3) & 3;
    const int nl = t >> 5;               // 0..7
    const int bx = blockIdx.x;
    const int n0 = (bx >> 3) * BN;
    const int ms = bx & 7;
    const int n = n0 + nl;

    // --- per-thread constants (global, L2-hot) ---
    float qreg[DK];
    {
        const float* qp = qg + (size_t)n * DIM + h * DK;
        #pragma unroll
        for (int d4 = 0; d4 < 4; ++d4) {
            const float4 qv = *(const float4*)(qp + d4 * 4);
            qreg[d4 * 4 + 0] = qv.x; qreg[d4 * 4 + 1] = qv.y;
            qreg[d4 * 4 + 2] = qv.z; qreg[d4 * 4 + 3] = qv.w;
        }
    }
    float waec[EDIM];
    #pragma unroll
    for (int e = 0; e < EDIM; ++e) waec[e] = Wae[e * HEADS + h] * LOG2E;
    const float baeh = bae[h] * LOG2E;

    const int c = cnt[n];
    const unsigned short* ip = idx + (size_t)n * NNODE;
    const float* efn = ef + (size_t)n * NNODE * EDIM;

    float sl = 0.f, accv[DK], accT[EDIM];
    #pragma unroll
    for (int d = 0; d < DK; ++d) accv[d] = 0.f;
    #pragma unroll
    for (int e = 0; e < EDIM; ++e) accT[e] = 0.f;

    // --- main loop over this thread's slice of the valid-m list ---
    int i = ms * 4 + mslot;
    int m = (i < c) ? (int)ip[i] : 0;
    #pragma unroll 1
    while (i < c) {
        const int inext = i + 32;
        const int mnext = (inext < c) ? (int)ip[inext] : 0;   // prefetched early

        const float* kp = kg + (size_t)m * DIM + h * DK;
        const float* vp = vg + (size_t)m * DIM + h * DK;
        const float* ep = efn + (size_t)m * EDIM;
        float kk[DK], vv[DK], efv[EDIM];
        #pragma unroll
        for (int d4 = 0; d4 < 4; ++d4) {
            const float4 k4 = *(const float4*)(kp + d4 * 4);
            kk[d4 * 4 + 0] = k4.x; kk[d4 * 4 + 1] = k4.y;
            kk[d4 * 4 + 2] = k4.z; kk[d4 * 4 + 3] = k4.w;
            const float4 v4 = *(const float4*)(vp + d4 * 4);
            vv[d4 * 4 + 0] = v4.x; vv[d4 * 4 + 1] = v4.y;
            vv[d4 * 4 + 2] = v4.z; vv[d4 * 4 + 3] = v4.w;
            const float4 e4 = *(const float4*)(ep + d4 * 4);   // octet broadcast
            efv[d4 * 4 + 0] = e4.x; efv[d4 * 4 + 1] = e4.y;
            efv[d4 * 4 + 2] = e4.z; efv[d4 * 4 + 3] = e4.w;
        }
        float bias = baeh, dot = 0.f;
        #pragma unroll
        for (int e = 0; e < EDIM; ++e) bias = fmaf(efv[e], waec[e], bias);
        #pragma unroll
        for (int d = 0; d < DK; ++d) dot = fmaf(qreg[d], kk[d], dot);
        const float p = __builtin_amdgcn_exp2f(fmaf(dot, 0.25f * LOG2E, bias));
        sl += p;
        #pragma unroll
        for (int d = 0; d < DK; ++d) accv[d] = fmaf(p, vv[d], accv[d]);
        #pragma unroll
        for (int e = 0; e < EDIM; ++e) accT[e] = fmaf(p, efv[e], accT[e]);

        i = inext; m = mnext;
    }

    // --- reduce over the 4 mslots (lane bits 3,4), then atomics from mslot==0 ---
    #pragma unroll
    for (int off = 8; off <= 16; off <<= 1) {
        sl += __shfl_xor(sl, off);
        #pragma unroll
        for (int d = 0; d < DK; ++d) accv[d] += __shfl_xor(accv[d], off);
        #pragma unroll
        for (int e = 0; e < EDIM; ++e) accT[e] += __shfl_xor(accT[e], off);
    }
    if (mslot == 0) {
        float* ap = acc + ((size_t)n * HEADS + h) * 33;
        atomicAdd(&ap[0], sl);
        #pragma unroll
        for (int d = 0; d < DK; ++d) atomicAdd(&ap[1 + d], accv[d]);
        #pragma unroll
        for (int e = 0; e < EDIM; ++e) atomicAdd(&ap[17 + e], accT[e]);
    }
}

// ---------------- Kernel 3: epilogue (Wve, normalize, Wo, residual) ----------------
__global__ __launch_bounds__(128)
void final_kernel(const float* __restrict__ acc,
                  const float* __restrict__ Wve, const float* __restrict__ bve,
                  const float* __restrict__ x,
                  const float* __restrict__ Wo, const float* __restrict__ bo,
                  float* __restrict__ out) {
    const int n = blockIdx.x, t = threadIdx.x;
    __shared__ float ab[HEADS * 33];
    __shared__ float orow[DIM];
    for (int u = t; u < HEADS * 33; u += 128) ab[u] = acc[(size_t)n * HEADS * 33 + u];
    __syncthreads();
    const int col = t, hh = col >> 4, dd = col & 15;
    const float slv = ab[hh * 33];
    float acc2 = 0.f;
    #pragma unroll
    for (int e = 0; e < EDIM; ++e) acc2 = fmaf(ab[hh * 33 + 17 + e], Wve[e * DIM + col], acc2);
    orow[col] = (ab[hh * 33 + 1 + dd] + acc2) / slv + bve[col];
    __syncthreads();
    float o = bo[col] + x[(size_t)n * DIM + col];
    #pragma unroll 16
    for (int i = 0; i < DIM; ++i) o = fmaf(orow[i], Wo[i * DIM + col], o);
    out[(size_t)n * DIM + col] = o;
}

extern "C" void kernel_launch(void* const* d_in, const int* in_sizes, int n_in,
                              void* d_out, int out_size, void* d_ws, size_t ws_size,
                              hipStream_t stream) {
    const float* x     = (const float*)d_in[0];
    const float* ef    = (const float*)d_in[1];
    const int*   mask  = (const int*)d_in[2];
    const float* Wq    = (const float*)d_in[3];
    const float* bq    = (const float*)d_in[4];
    const float* Wk    = (const float*)d_in[5];
    const float* bk    = (const float*)d_in[6];
    const float* Wv    = (const float*)d_in[7];
    const float* bv    = (const float*)d_in[8];
    const float* Wae   = (const float*)d_in[9];
    const float* bae   = (const float*)d_in[10];
    const float* Wve   = (const float*)d_in[11];
    const float* bve   = (const float*)d_in[12];
    const float* Wo    = (const float*)d_in[13];
    const float* bo    = (const float*)d_in[14];
    const float* gamma = (const float*)d_in[15];
    const float* beta  = (const float*)d_in[16];

    float* ws = (float*)d_ws;
    float* accb = ws;                                   // 1024*8*33 = 270336 f32
    float* qg   = ws + 270336;
    float* kg   = qg + (size_t)NNODE * DIM;
    float* vg   = kg + (size_t)NNODE * DIM;
    unsigned short* idxb = (unsigned short*)(vg + (size_t)NNODE * DIM);  // 2 MB
    int* cntb = (int*)(idxb + (size_t)NNODE * NNODE);                    // 4 KB

    hipMemsetAsync(accb, 0, (size_t)NNODE * HEADS * 33 * sizeof(float), stream);
    mask_scan_kernel<<<NNODE, 64, 0, stream>>>(mask, idxb, cntb);
    ln_qkv_kernel<<<NNODE, 384, 0, stream>>>(x, Wq, bq, Wk, bk, Wv, bv, gamma, beta, qg, kg, vg);
    attn_kernel<<<(NNODE / BN) * MSPLIT, 256, 0, stream>>>(qg, kg, vg, ef, idxb, cntb,
                                                          Wae, bae, accb);
    final_kernel<<<NNODE, 128, 0, stream>>>(accb, Wve, bve, x, Wo, bo, (float*)d_out);
}